// Round 15
// baseline (2453.348 us; speedup 1.0000x reference)
//
#include <hip/hip_runtime.h>

typedef float v2f __attribute__((ext_vector_type(2)));
typedef unsigned uv2 __attribute__((ext_vector_type(2)));

constexpr int NX = 32, NU = 16, NF = 512;
constexpr int SEQ = 2048;
constexpr int NT = 128;           // 2 waves/block; 1 row/block; 4 features/thread
constexpr float SC  = 2.88539008177792681f;  // 2/ln2: tanh(a) = 1 - 2/(exp2(SC*a)+1)
constexpr float TSC = 0.01f;

// DPP partner read (VALU pipe). Direction-proof controls only:
// 0xB1 quad_perm xor1 | 0x4E quad_perm xor2 | 0x128 row_ror:8 (= xor8 both directions)
template<int CTRL>
__device__ __forceinline__ float dpp_mov(float v) {
    return __int_as_float(__builtin_amdgcn_update_dpp(0, __float_as_int(v), CTRL, 0xF, 0xF, true));
}
// gfx950 permlane swaps (VALU pipe): v[l] + v[l^16] / v[l^32]
__device__ __forceinline__ float sum16(float v) {
    uv2 r = __builtin_amdgcn_permlane16_swap(__float_as_uint(v), __float_as_uint(v), false, false);
    return __uint_as_float(r.x) + __uint_as_float(r.y);
}
__device__ __forceinline__ float sum32(float v) {
    uv2 r = __builtin_amdgcn_permlane32_swap(__float_as_uint(v), __float_as_uint(v), false, false);
    return __uint_as_float(r.x) + __uint_as_float(r.y);
}

__device__ __forceinline__ float tanh4(float y) {       // y pre-scaled by SC
    const float e = __builtin_amdgcn_exp2f(y);
    const float r = __builtin_amdgcn_rcpf(e + 1.f);
    return fmaf(-2.f, r, 1.f);
}

// LDS-only barrier: no vmcnt drain (out-stores / u-prefetch stay in flight)
__device__ __forceinline__ void bar_lds() {
    asm volatile("s_waitcnt lgkmcnt(0)" ::: "memory");
    __builtin_amdgcn_sched_barrier(0);
    __builtin_amdgcn_s_barrier();
    __builtin_amdgcn_sched_barrier(0);
    asm volatile("" ::: "memory");
}

__global__ __launch_bounds__(NT)
__attribute__((amdgpu_waves_per_eu(1, 1)))   // 1 wave/SIMD, full 512-reg unified budget
void fes_kernel(const float* __restrict__ x0, const float* __restrict__ ug,
                const float* __restrict__ W1, const float* __restrict__ b1,
                const float* __restrict__ W2, const float* __restrict__ b2,
                float* __restrict__ out)
{
    __shared__ __align__(16) float xs_w[2][NX];     // per-wave private state copies
    __shared__ __align__(16) float part[2][NX][12]; // ping-pong; slots 0..3 used, stride 12 (48B, aligned)

    const int tid = threadIdx.x, row = blockIdx.x;
    const int l = tid & 63, w = tid >> 6;           // 2 waves

    // lane -> owned output j (XOR-linear): pi(1)=16, pi(2)=8, pi(8)=4, pi(16)=2, pi(32)=1, pi(4)=0
    const int pi = ((l & 1) << 4) | (((l >> 1) & 1) << 3) | (((l >> 3) & 1) << 2)
                 | (((l >> 4) & 1) << 1) | ((l >> 5) & 1);
    const int slot = 2 * w + ((l >> 2) & 1);        // 2 waves x 2 cosets = 4 partials/j
    const bool jown = (l & 4) == 0;
    const bool store_lane = (w == 0) && jown;

    const int fb = 4 * tid;                         // this thread's 4 features

    // ---- persistent registers --------------------------------------------
    // G1 weights, k-parity pairs: wk[c][p] covers k = 2p, 2p+1 (k=0..47) for feature fb+c
    v2f wk[4][24];
#pragma unroll
    for (int c = 0; c < 4; ++c)
#pragma unroll
        for (int p = 0; p < 24; ++p)
            wk[c][p] = v2f{SC * W1[(2 * p) * NF + fb + c],
                           SC * W1[(2 * p + 1) * NF + fb + c]};
    float b1r[4];
#pragma unroll
    for (int c = 0; c < 4; ++c) b1r[c] = SC * b1[fb + c];

    // G2 weights, pi-domain: position p holds j = p ^ pi
    v2f wc[4][16];
#pragma unroll
    for (int c = 0; c < 4; ++c)
#pragma unroll
        for (int m = 0; m < 16; ++m)
            wc[c][m] = v2f{TSC * W2[(fb + c) * NX + ((2 * m) ^ pi)],
                           TSC * W2[(fb + c) * NX + ((2 * m + 1) ^ pi)]};
    const float bb = TSC * b2[pi];
    float xr = x0[row * NX + pi];                   // lane-resident state element

    const float* ug_row  = ug  + (size_t)row * SEQ * NU;
    float*       out_row = out + (size_t)row * SEQ * NX;

    if (jown) xs_w[w][pi] = xr;                     // wave-private: in-wave ordering suffices
    float4 u0 = *(const float4*)(ug_row + 0);
    float4 u1 = *(const float4*)(ug_row + 4);
    float4 u2 = *(const float4*)(ug_row + 8);
    float4 u3 = *(const float4*)(ug_row + 12);

    const float4* xsr = (const float4*)xs_w[w];

#pragma unroll 1
    for (int t = 0; t < SEQ; ++t) {
        // ---- G1: 4 features, 4 independent chains (8 uniform b128 + reg u)
        v2f ae[4], ao[4];
#pragma unroll
        for (int c = 0; c < 4; ++c) { ae[c] = v2f{b1r[c], 0.f}; ao[c] = v2f{0.f, 0.f}; }
#pragma unroll
        for (int s = 0; s < 8; ++s) {
            const float4 iv = xsr[s];               // wave-uniform broadcast
            const v2f lo = {iv.x, iv.y}, hi = {iv.z, iv.w};
#pragma unroll
            for (int c = 0; c < 4; ++c) {
                ae[c] += wk[c][2 * s] * lo;
                ao[c] += wk[c][2 * s + 1] * hi;
            }
        }
#define UQ(uv, qd)                                                          \
        {   const v2f lo = {uv.x, uv.y}, hi = {uv.z, uv.w};                 \
            _Pragma("unroll")                                               \
            for (int c = 0; c < 4; ++c) {                                   \
                ae[c] += wk[c][16 + 2 * (qd)] * lo;                         \
                ao[c] += wk[c][17 + 2 * (qd)] * hi;                         \
            } }
        UQ(u0, 0) UQ(u1, 1) UQ(u2, 2) UQ(u3, 3)
#undef UQ
        // prefetch next u (no vmcnt drain at barrier -> true overlap)
        {
            const int tn = (t + 1 < SEQ) ? t + 1 : SEQ - 1;
            const float* un = ug_row + (size_t)tn * NU;
            u0 = *(const float4*)(un + 0);
            u1 = *(const float4*)(un + 4);
            u2 = *(const float4*)(un + 8);
            u3 = *(const float4*)(un + 12);
        }
        float h[4];
#pragma unroll
        for (int c = 0; c < 4; ++c)
            h[c] = tanh4((ae[c].x + ae[c].y) + (ao[c].x + ao[c].y));

        // ---- G2: pi-domain partials over 4 features (64 pk-fma) ----------
        v2f q[16];
#pragma unroll
        for (int m = 0; m < 16; ++m) {
            v2f acc = v2f{h[0], h[0]} * wc[0][m];
            acc += v2f{h[1], h[1]} * wc[1][m];
            acc += v2f{h[2], h[2]} * wc[2][m];
            acc += v2f{h[3], h[3]} * wc[3][m];
            q[m] = acc;
        }

        // ---- in-wave reduce-scatter (direction-proof ops only) -----------
#pragma unroll
        for (int m = 0; m < 8; ++m) {                 // d=1 (j-bit 16)
            q[m].x += dpp_mov<0xB1>(q[m + 8].x);
            q[m].y += dpp_mov<0xB1>(q[m + 8].y);
        }
#pragma unroll
        for (int m = 0; m < 4; ++m) {                 // d=2 (j-bit 8)
            q[m].x += dpp_mov<0x4E>(q[m + 4].x);
            q[m].y += dpp_mov<0x4E>(q[m + 4].y);
        }
#pragma unroll
        for (int m = 0; m < 2; ++m) {                 // d=8 (j-bit 4)
            q[m].x += dpp_mov<0x128>(q[m + 2].x);
            q[m].y += dpp_mov<0x128>(q[m + 2].y);
        }
        // d=16 (j-bit 2), d=32 (j-bit 1): partner = sum - self
        const float S0 = q[0].x + (sum16(q[1].x) - q[1].x);
        const float S1 = q[0].y + (sum16(q[1].y) - q[1].y);
        const float S  = S0 + (sum32(S1) - S1);
        // d=4 not folded: both coset lanes write their partial (4 slots/j total)

        // ---- cross-wave combine: 1 write, 2-wave barrier, 1 b128 read ----
        part[t & 1][pi][slot] = S;
        bar_lds();
        const float4 pv = *(const float4*)&part[t & 1][pi][0];
        const float xn = xr + ((pv.x + pv.y) + (pv.z + pv.w)) + bb;
        xr = xn;
        if (store_lane) out_row[(size_t)t * NX + pi] = xn;
        if (jown) xs_w[w][pi] = xn;                 // own wave's copy (in-wave ordered)
    }
}

extern "C" void kernel_launch(void* const* d_in, const int* in_sizes, int n_in,
                              void* d_out, int out_size, void* d_ws, size_t ws_size,
                              hipStream_t stream) {
    const float* x0 = (const float*)d_in[0];
    const float* ug = (const float*)d_in[1];
    const float* W1 = (const float*)d_in[2];
    const float* b1 = (const float*)d_in[3];
    const float* W2 = (const float*)d_in[4];
    const float* b2 = (const float*)d_in[5];
    float* out = (float*)d_out;

    fes_kernel<<<dim3(512), dim3(NT), 0, stream>>>(x0, ug, W1, b1, W2, b2, out);
}